// Round 13
// baseline (92.712 us; speedup 1.0000x reference)
//
#include <hip/hip_runtime.h>

// SpectralDivergence: fft2(512x512) power spectrum -> radial profile (50 bins)
// -> per-batch KL divergence between softmaxed profiles of x and reference.
// 96 images (48 x + 48 ref), B=16, C=3, H=W=512. Output: 16 floats.
//
// R13: R11's SPLIT (fastest col-side measured: colspow+binpow ~36us combined)
// with the poison removed. R11 wrote power IN-PLACE over interT; next
// replay's rows kernel then rewrote those dirty lines -> rows 15->53us.
// Now: interT written ONLY by rows; power goes to a SEPARATE powerbuf
// (single writer per buffer). Chunked at ~1.03MB/img to fit any ws_size.
// Pre-commit: rows steady <=20us & total 55-65us, else dirty-line theory is
// refuted and rows gets isolated next round.

#define NIMG 96
#define NB 50
#define NCOL 257
#define PHYS(k) ((k) ^ (((k) >> 3) & 7))

typedef unsigned int uint32;

__device__ __forceinline__ float2 cadd(float2 a, float2 b){ return make_float2(a.x+b.x, a.y+b.y); }
__device__ __forceinline__ float2 csub(float2 a, float2 b){ return make_float2(a.x-b.x, a.y-b.y); }
__device__ __forceinline__ float2 cmul(float2 a, float2 b){
  return make_float2(fmaf(a.x, b.x, -(a.y*b.y)), fmaf(a.x, b.y, a.y*b.x));
}
__device__ __forceinline__ float2 mul_mi(float2 a){ return make_float2(a.y, -a.x); }  // * -i

// pack complex -> bf16x2 (re high, im low), RNE
__device__ __forceinline__ uint32 bfpack(float re, float im) {
  uint32 ur = __float_as_uint(re); ur += 0x7FFFu + ((ur >> 16) & 1u);
  uint32 ui = __float_as_uint(im); ui += 0x7FFFu + ((ui >> 16) & 1u);
  return (ur & 0xFFFF0000u) | (ui >> 16);
}
__device__ __forceinline__ float2 bfunpack(uint32 u) {
  return make_float2(__uint_as_float(u & 0xFFFF0000u), __uint_as_float(u << 16));
}

// 8 complex values in named registers.
struct C8 { float2 m0, m1, m2, m3, m4, m5, m6, m7; };

// 8-point DFT, natural order (by value).
__device__ __forceinline__ C8 fft8(C8 v) {
  const float C = 0.70710678118654752f;
  float2 t0=cadd(v.m0,v.m4), t1=csub(v.m0,v.m4);
  float2 t2=cadd(v.m2,v.m6), t3m=mul_mi(csub(v.m2,v.m6));
  float2 E0=cadd(t0,t2), E1=cadd(t1,t3m), E2=csub(t0,t2), E3=csub(t1,t3m);
  float2 s0=cadd(v.m1,v.m5), s1=csub(v.m1,v.m5);
  float2 s2=cadd(v.m3,v.m7), s3m=mul_mi(csub(v.m3,v.m7));
  float2 O0=cadd(s0,s2), O1=cadd(s1,s3m), O2=csub(s0,s2), O3=csub(s1,s3m);
  O1 = make_float2(C*(O1.x+O1.y), C*(O1.y-O1.x));      // * W8^1
  O2 = mul_mi(O2);                                      // * W8^2
  O3 = make_float2(C*(O3.y-O3.x), -C*(O3.x+O3.y));      // * W8^3
  C8 r;
  r.m0=cadd(E0,O0); r.m4=csub(E0,O0);
  r.m1=cadd(E1,O1); r.m5=csub(E1,O1);
  r.m2=cadd(E2,O2); r.m6=csub(E2,O2);
  r.m3=cadd(E3,O3); r.m7=csub(E3,O3);
  return r;
}

// twiddle recurrence applied to members 1..7 of XA and XB (shared t chain)
#define TWAPPLY(XA, XB, W) do { float2 t_ = (W);                        \
  XA.m1=cmul(XA.m1,t_); XB.m1=cmul(XB.m1,t_); t_=cmul(t_,(W));          \
  XA.m2=cmul(XA.m2,t_); XB.m2=cmul(XB.m2,t_); t_=cmul(t_,(W));          \
  XA.m3=cmul(XA.m3,t_); XB.m3=cmul(XB.m3,t_); t_=cmul(t_,(W));          \
  XA.m4=cmul(XA.m4,t_); XB.m4=cmul(XB.m4,t_); t_=cmul(t_,(W));          \
  XA.m5=cmul(XA.m5,t_); XB.m5=cmul(XB.m5,t_); t_=cmul(t_,(W));          \
  XA.m6=cmul(XA.m6,t_); XB.m6=cmul(XB.m6,t_); t_=cmul(t_,(W));          \
  XA.m7=cmul(XA.m7,t_); XB.m7=cmul(XB.m7,t_); } while(0)

// Dual wave-local 512-pt FFT (two independent FFTs, phase-interleaved).
#define DUAL_FFT512(XA, XB, ZA, ZB, W1, W2, HI, LO) do {                      \
  XA = fft8(XA); XB = fft8(XB);                                               \
  TWAPPLY(XA, XB, W1);                                                        \
  ZA[      8*((HI)^0)+(LO)] = XA.m0;  ZB[      8*((HI)^0)+(LO)] = XB.m0;      \
  ZA[ 64 + 8*((HI)^1)+(LO)] = XA.m1;  ZB[ 64 + 8*((HI)^1)+(LO)] = XB.m1;      \
  ZA[128 + 8*((HI)^2)+(LO)] = XA.m2;  ZB[128 + 8*((HI)^2)+(LO)] = XB.m2;      \
  ZA[192 + 8*((HI)^3)+(LO)] = XA.m3;  ZB[192 + 8*((HI)^3)+(LO)] = XB.m3;      \
  ZA[256 + 8*((HI)^4)+(LO)] = XA.m4;  ZB[256 + 8*((HI)^4)+(LO)] = XB.m4;      \
  ZA[320 + 8*((HI)^5)+(LO)] = XA.m5;  ZB[320 + 8*((HI)^5)+(LO)] = XB.m5;      \
  ZA[384 + 8*((HI)^6)+(LO)] = XA.m6;  ZB[384 + 8*((HI)^6)+(LO)] = XB.m6;      \
  ZA[448 + 8*((HI)^7)+(LO)] = XA.m7;  ZB[448 + 8*((HI)^7)+(LO)] = XB.m7;      \
  __builtin_amdgcn_wave_barrier();                                            \
  XA.m0 = ZA[64*(HI)+8*(0^(HI))+(LO)]; XB.m0 = ZB[64*(HI)+8*(0^(HI))+(LO)];   \
  XA.m1 = ZA[64*(HI)+8*(1^(HI))+(LO)]; XB.m1 = ZB[64*(HI)+8*(1^(HI))+(LO)];   \
  XA.m2 = ZA[64*(HI)+8*(2^(HI))+(LO)]; XB.m2 = ZB[64*(HI)+8*(2^(HI))+(LO)];   \
  XA.m3 = ZA[64*(HI)+8*(3^(HI))+(LO)]; XB.m3 = ZB[64*(HI)+8*(3^(HI))+(LO)];   \
  XA.m4 = ZA[64*(HI)+8*(4^(HI))+(LO)]; XB.m4 = ZB[64*(HI)+8*(4^(HI))+(LO)];   \
  XA.m5 = ZA[64*(HI)+8*(5^(HI))+(LO)]; XB.m5 = ZB[64*(HI)+8*(5^(HI))+(LO)];   \
  XA.m6 = ZA[64*(HI)+8*(6^(HI))+(LO)]; XB.m6 = ZB[64*(HI)+8*(6^(HI))+(LO)];   \
  XA.m7 = ZA[64*(HI)+8*(7^(HI))+(LO)]; XB.m7 = ZB[64*(HI)+8*(7^(HI))+(LO)];   \
  __builtin_amdgcn_wave_barrier();                                            \
  XA = fft8(XA); XB = fft8(XB);                                               \
  TWAPPLY(XA, XB, W2);                                                        \
  ZA[64*(HI)+8*(0^(HI))+((LO)^0)] = XA.m0; ZB[64*(HI)+8*(0^(HI))+((LO)^0)] = XB.m0; \
  ZA[64*(HI)+8*(1^(HI))+((LO)^1)] = XA.m1; ZB[64*(HI)+8*(1^(HI))+((LO)^1)] = XB.m1; \
  ZA[64*(HI)+8*(2^(HI))+((LO)^2)] = XA.m2; ZB[64*(HI)+8*(2^(HI))+((LO)^2)] = XB.m2; \
  ZA[64*(HI)+8*(3^(HI))+((LO)^3)] = XA.m3; ZB[64*(HI)+8*(3^(HI))+((LO)^3)] = XB.m3; \
  ZA[64*(HI)+8*(4^(HI))+((LO)^4)] = XA.m4; ZB[64*(HI)+8*(4^(HI))+((LO)^4)] = XB.m4; \
  ZA[64*(HI)+8*(5^(HI))+((LO)^5)] = XA.m5; ZB[64*(HI)+8*(5^(HI))+((LO)^5)] = XB.m5; \
  ZA[64*(HI)+8*(6^(HI))+((LO)^6)] = XA.m6; ZB[64*(HI)+8*(6^(HI))+((LO)^6)] = XB.m6; \
  ZA[64*(HI)+8*(7^(HI))+((LO)^7)] = XA.m7; ZB[64*(HI)+8*(7^(HI))+((LO)^7)] = XB.m7; \
  __builtin_amdgcn_wave_barrier();                                            \
  XA.m0 = ZA[64*(HI)+8*((LO)^(HI))+(0^(LO))]; XB.m0 = ZB[64*(HI)+8*((LO)^(HI))+(0^(LO))]; \
  XA.m1 = ZA[64*(HI)+8*((LO)^(HI))+(1^(LO))]; XB.m1 = ZB[64*(HI)+8*((LO)^(HI))+(1^(LO))]; \
  XA.m2 = ZA[64*(HI)+8*((LO)^(HI))+(2^(LO))]; XB.m2 = ZB[64*(HI)+8*((LO)^(HI))+(2^(LO))]; \
  XA.m3 = ZA[64*(HI)+8*((LO)^(HI))+(3^(LO))]; XB.m3 = ZB[64*(HI)+8*((LO)^(HI))+(3^(LO))]; \
  XA.m4 = ZA[64*(HI)+8*((LO)^(HI))+(4^(LO))]; XB.m4 = ZB[64*(HI)+8*((LO)^(HI))+(4^(LO))]; \
  XA.m5 = ZA[64*(HI)+8*((LO)^(HI))+(5^(LO))]; XB.m5 = ZB[64*(HI)+8*((LO)^(HI))+(5^(LO))]; \
  XA.m6 = ZA[64*(HI)+8*((LO)^(HI))+(6^(LO))]; XB.m6 = ZB[64*(HI)+8*((LO)^(HI))+(6^(LO))]; \
  XA.m7 = ZA[64*(HI)+8*((LO)^(HI))+(7^(LO))]; XB.m7 = ZB[64*(HI)+8*((LO)^(HI))+(7^(LO))]; \
  __builtin_amdgcn_wave_barrier();                                            \
  XA = fft8(XA); XB = fft8(XB);                                               \
} while(0)

#define TWIDDLE_W(W1, W2, lane)                                             \
  float2 W1, W2;                                                            \
  {                                                                         \
    float sv, cv;                                                           \
    __sincosf(-6.283185307179586f * (float)(lane) / 512.f, &sv, &cv);       \
    W1 = make_float2(cv, sv);                                               \
    __sincosf(-6.283185307179586f * (float)((lane) & 7) / 64.f, &sv, &cv);  \
    W2 = make_float2(cv, sv);                                               \
  }

// bin of a pixel at |sy|=s in column c
__device__ __forceinline__ int binOf(int s, int cc) {
  return (int)(sqrtf((float)(s * s + cc * cc)) * 0.1953125f);
}
// smallest s in [0,257] with binOf(s,cc) >= b
__device__ __forceinline__ int slo(int b, int cc) {
  if (b <= 0) return 0;
  float t = 26.2144f * (float)(b * b) - (float)(cc * cc);
  int s = (t <= 0.f) ? 0 : (int)ceilf(sqrtf(t));
  if (s > 257) s = 257;
  while (s > 0 && binOf(s - 1, cc) >= b) --s;
  while (s < 257 && binOf(s, cc) < b) ++s;
  return s;
}

// ---------------------------------------------------------------------------
// Row pass (R8 verbatim). interT is written ONLY here.
// ---------------------------------------------------------------------------
__global__ __launch_bounds__(256, 4) void fft_rows_T(
    const float* __restrict__ xin, const float* __restrict__ rin,
    uint32* __restrict__ outT, int img0)
{
  __shared__ float2 s_z[8][512];
  __shared__ uint2  s_stage[64][8];
  const int tid = threadIdx.x, w = tid >> 6, lane = tid & 63;
  const int hi = lane >> 3, lo = lane & 7;
  const int imgL = blockIdx.x >> 5, blkin = blockIdx.x & 31;
  const int img = img0 + imgL;
  const float* base = (img < 48) ? (xin + (size_t)img * 262144)
                                 : (rin + (size_t)(img - 48) * 262144);
  const int rpA = blkin * 8 + w;
  const int rpB = rpA + 4;
  const float* srcA = base + (size_t)rpA * 1024;
  const float* srcB = base + (size_t)rpB * 1024;

  TWIDDLE_W(w1, w2, lane)
  float2* zA = s_z[2*w];
  float2* zB = s_z[2*w + 1];
  uint32* outImg = outT + (size_t)imgL * ((size_t)NCOL * 512);

  C8 xA, xB;
  xA.m0 = make_float2(srcA[      lane], srcA[512 +       lane]);
  xA.m1 = make_float2(srcA[ 64 + lane], srcA[512 +  64 + lane]);
  xA.m2 = make_float2(srcA[128 + lane], srcA[512 + 128 + lane]);
  xA.m3 = make_float2(srcA[192 + lane], srcA[512 + 192 + lane]);
  xA.m4 = make_float2(srcA[256 + lane], srcA[512 + 256 + lane]);
  xA.m5 = make_float2(srcA[320 + lane], srcA[512 + 320 + lane]);
  xA.m6 = make_float2(srcA[384 + lane], srcA[512 + 384 + lane]);
  xA.m7 = make_float2(srcA[448 + lane], srcA[512 + 448 + lane]);
  xB.m0 = make_float2(srcB[      lane], srcB[512 +       lane]);
  xB.m1 = make_float2(srcB[ 64 + lane], srcB[512 +  64 + lane]);
  xB.m2 = make_float2(srcB[128 + lane], srcB[512 + 128 + lane]);
  xB.m3 = make_float2(srcB[192 + lane], srcB[512 + 192 + lane]);
  xB.m4 = make_float2(srcB[256 + lane], srcB[512 + 256 + lane]);
  xB.m5 = make_float2(srcB[320 + lane], srcB[512 + 320 + lane]);
  xB.m6 = make_float2(srcB[384 + lane], srcB[512 + 384 + lane]);
  xB.m7 = make_float2(srcB[448 + lane], srcB[512 + 448 + lane]);

  DUAL_FFT512(xA, xB, zA, zB, w1, w2, hi, lo);

  zA[PHYS(hi + 8*lo +   0)] = xA.m0;  zB[PHYS(hi + 8*lo +   0)] = xB.m0;
  zA[PHYS(hi + 8*lo +  64)] = xA.m1;  zB[PHYS(hi + 8*lo +  64)] = xB.m1;
  zA[PHYS(hi + 8*lo + 128)] = xA.m2;  zB[PHYS(hi + 8*lo + 128)] = xB.m2;
  zA[PHYS(hi + 8*lo + 192)] = xA.m3;  zB[PHYS(hi + 8*lo + 192)] = xB.m3;
  zA[PHYS(hi + 8*lo + 256)] = xA.m4;  zB[PHYS(hi + 8*lo + 256)] = xB.m4;
  zA[PHYS(hi + 8*lo + 320)] = xA.m5;  zB[PHYS(hi + 8*lo + 320)] = xB.m5;
  zA[PHYS(hi + 8*lo + 384)] = xA.m6;  zB[PHYS(hi + 8*lo + 384)] = xB.m6;
  zA[PHYS(hi + 8*lo + 448)] = xA.m7;  zB[PHYS(hi + 8*lo + 448)] = xB.m7;
  __builtin_amdgcn_wave_barrier();

  #pragma unroll
  for (int a = 0; a < 4; ++a) {
    const int k  = 64 * a + lane;
    const int pk = (512 - k) & 511;
    float2 zkA = zA[PHYS(k)], zpA = zA[PHYS(pk)];
    float2 zkB = zB[PHYS(k)], zpB = zB[PHYS(pk)];
    uint32 uA0 = bfpack(0.5f*(zkA.x + zpA.x), 0.5f*(zkA.y - zpA.y));
    uint32 uA1 = bfpack(0.5f*(zkA.y + zpA.y), 0.5f*(zpA.x - zkA.x));
    uint32 uB0 = bfpack(0.5f*(zkB.x + zpB.x), 0.5f*(zkB.y - zpB.y));
    uint32 uB1 = bfpack(0.5f*(zkB.y + zpB.y), 0.5f*(zpB.x - zkB.x));
    s_stage[lane][(w + lane) & 7]     = make_uint2(uA0, uA1);
    s_stage[lane][(w + 4 + lane) & 7] = make_uint2(uB0, uB1);
    __syncthreads();
    const int kk = tid >> 2, jj = (tid & 3) * 2;
    uint2 v0 = s_stage[kk][(jj + kk) & 7];
    uint2 v1 = s_stage[kk][(jj + 1 + kk) & 7];
    *reinterpret_cast<uint4*>(outImg + ((size_t)(64*a + kk) * 512
                                        + 16*blkin + 2*jj)) =
        make_uint4(v0.x, v0.y, v1.x, v1.y);
    __syncthreads();
  }
  if (lane == 0) {
    float2 znA = zA[256], znB = zB[256];
    *reinterpret_cast<uint2*>(outImg + ((size_t)256 * 512 + 2 * rpA)) =
        make_uint2(bfpack(znA.x, 0.f), bfpack(znA.y, 0.f));
    *reinterpret_cast<uint2*>(outImg + ((size_t)256 * 512 + 2 * rpB)) =
        make_uint2(bfpack(znB.x, 0.f), bfpack(znB.y, 0.f));
  }
}

// ---------------------------------------------------------------------------
// Col FFT pass: TWO column FFTs per wave; writes fp32 POWER to a SEPARATE
// powerbuf (interT stays clean/read-only downstream of rows). Per-q store
// addresses are a permutation of one 256B segment -> fully coalesced.
// Clamped duplicate columns (c>256) skip the write.
// ---------------------------------------------------------------------------
__global__ __launch_bounds__(256, 4) void fft_cols_pow(
    const uint32* __restrict__ inT, float* __restrict__ pw, int img0)
{
  __shared__ float2 s_z[8][512];
  const int tid = threadIdx.x, w = tid >> 6, lane = tid & 63;
  const int hi = lane >> 3, lo = lane & 7;
  const int imgL = blockIdx.x / 33, blkin = blockIdx.x - imgL * 33;
  const int cA = blkin * 8 + w;
  const int cB = cA + 4;
  const int csA = (cA <= 256) ? cA : 256;
  const int csB = (cB <= 256) ? cB : 256;

  TWIDDLE_W(w1, w2, lane)
  float2* zA = s_z[2*w];
  float2* zB = s_z[2*w + 1];
  const uint32* srcA = inT + ((size_t)(imgL * NCOL + csA)) * 512;
  const uint32* srcB = inT + ((size_t)(imgL * NCOL + csB)) * 512;
  C8 xA, xB;
  xA.m0 = bfunpack(srcA[      lane]);  xB.m0 = bfunpack(srcB[      lane]);
  xA.m1 = bfunpack(srcA[ 64 + lane]);  xB.m1 = bfunpack(srcB[ 64 + lane]);
  xA.m2 = bfunpack(srcA[128 + lane]);  xB.m2 = bfunpack(srcB[128 + lane]);
  xA.m3 = bfunpack(srcA[192 + lane]);  xB.m3 = bfunpack(srcB[192 + lane]);
  xA.m4 = bfunpack(srcA[256 + lane]);  xB.m4 = bfunpack(srcB[256 + lane]);
  xA.m5 = bfunpack(srcA[320 + lane]);  xB.m5 = bfunpack(srcB[320 + lane]);
  xA.m6 = bfunpack(srcA[384 + lane]);  xB.m6 = bfunpack(srcB[384 + lane]);
  xA.m7 = bfunpack(srcA[448 + lane]);  xB.m7 = bfunpack(srcB[448 + lane]);

  DUAL_FFT512(xA, xB, zA, zB, w1, w2, hi, lo);

  const int low6 = hi + 8 * lo;
  if (cA <= 256) {
    float* pA = pw + ((size_t)(imgL * NCOL + cA)) * 512;
    pA[low6      ] = xA.m0.x*xA.m0.x + xA.m0.y*xA.m0.y;
    pA[low6 +  64] = xA.m1.x*xA.m1.x + xA.m1.y*xA.m1.y;
    pA[low6 + 128] = xA.m2.x*xA.m2.x + xA.m2.y*xA.m2.y;
    pA[low6 + 192] = xA.m3.x*xA.m3.x + xA.m3.y*xA.m3.y;
    pA[low6 + 256] = xA.m4.x*xA.m4.x + xA.m4.y*xA.m4.y;
    pA[low6 + 320] = xA.m5.x*xA.m5.x + xA.m5.y*xA.m5.y;
    pA[low6 + 384] = xA.m6.x*xA.m6.x + xA.m6.y*xA.m6.y;
    pA[low6 + 448] = xA.m7.x*xA.m7.x + xA.m7.y*xA.m7.y;
  }
  if (cB <= 256) {
    float* pB = pw + ((size_t)(imgL * NCOL + cB)) * 512;
    pB[low6      ] = xB.m0.x*xB.m0.x + xB.m0.y*xB.m0.y;
    pB[low6 +  64] = xB.m1.x*xB.m1.x + xB.m1.y*xB.m1.y;
    pB[low6 + 128] = xB.m2.x*xB.m2.x + xB.m2.y*xB.m2.y;
    pB[low6 + 192] = xB.m3.x*xB.m3.x + xB.m3.y*xB.m3.y;
    pB[low6 + 256] = xB.m4.x*xB.m4.x + xB.m4.y*xB.m4.y;
    pB[low6 + 320] = xB.m5.x*xB.m5.x + xB.m5.y*xB.m5.y;
    pB[low6 + 384] = xB.m6.x*xB.m6.x + xB.m6.y*xB.m6.y;
    pB[low6 + 448] = xB.m7.x*xB.m7.x + xB.m7.y*xB.m7.y;
  }
}

// ---------------------------------------------------------------------------
// Binning pass: prefix-scan tail, own kernel, 17KB LDS -> ~8 blocks/CU.
// 2 columns per wave, 33 blocks/image.
// ---------------------------------------------------------------------------
__global__ __launch_bounds__(256, 8) void bin_pow(
    const float* __restrict__ pw, float* __restrict__ profSum, int img0)
{
  __shared__ float zf[4][2][512];   // 16 KB
  __shared__ float s_bins[4][64];   // 1 KB
  const int tid = threadIdx.x, w = tid >> 6, lane = tid & 63;
  const int imgL = blockIdx.x / 33, blkin = blockIdx.x - imgL * 33;
  const int imgG = img0 + imgL;
  const int cA = blkin * 8 + w;
  const int cB = cA + 4;
  const int csA = (cA <= 256) ? cA : 256;
  const int csB = (cB <= 256) ? cB : 256;
  const float wfA = (cA > 256) ? 0.f : ((cA == 0 || cA == 256) ? 1.f : 2.f);
  const float wfB = (cB > 256) ? 0.f : ((cB == 0 || cB == 256) ? 1.f : 2.f);

  const float* srcA = pw + ((size_t)(imgL * NCOL + csA)) * 512;
  const float* srcB = pw + ((size_t)(imgL * NCOL + csB)) * 512;
  float4 a0 = reinterpret_cast<const float4*>(srcA)[2 * lane];
  float4 a1 = reinterpret_cast<const float4*>(srcA)[2 * lane + 1];
  float4 b0 = reinterpret_cast<const float4*>(srcB)[2 * lane];
  float4 b1 = reinterpret_cast<const float4*>(srcB)[2 * lane + 1];

  // local inclusive prefix over 8
  a0.y += a0.x; a0.z += a0.y; a0.w += a0.z;
  a1.x += a0.w; a1.y += a1.x; a1.z += a1.y; a1.w += a1.z;
  b0.y += b0.x; b0.z += b0.y; b0.w += b0.z;
  b1.x += b0.w; b1.y += b1.x; b1.z += b1.y; b1.w += b1.z;
  float totA = a1.w, totB = b1.w;

  // wave inclusive scan of lane totals
  float sA = totA, sB = totB;
  #pragma unroll
  for (int d = 1; d < 64; d <<= 1) {
    float tA = __shfl_up(sA, d);
    float tB = __shfl_up(sB, d);
    if (lane >= d) { sA += tA; sB += tB; }
  }
  float offA = sA - totA, offB = sB - totB;
  a0.x += offA; a0.y += offA; a0.z += offA; a0.w += offA;
  a1.x += offA; a1.y += offA; a1.z += offA; a1.w += offA;
  b0.x += offB; b0.y += offB; b0.z += offB; b0.w += offB;
  b1.x += offB; b1.y += offB; b1.z += offB; b1.w += offB;

  float* zfA = zf[w][0];
  float* zfB = zf[w][1];
  *reinterpret_cast<float4*>(&zfA[8 * lane])     = a0;
  *reinterpret_cast<float4*>(&zfA[8 * lane + 4]) = a1;
  *reinterpret_cast<float4*>(&zfB[8 * lane])     = b0;
  *reinterpret_cast<float4*>(&zfB[8 * lane + 4]) = b1;
  __builtin_amdgcn_wave_barrier();

  // bin extraction: bin b = two prefix differences
  float acc = 0.f;
  if (lane < NB) {
    {
      int s0 = slo(lane, csA), s1 = slo(lane + 1, csA);
      int hp = (s1 < 257 ? s1 : 257) - 1;
      float pos = ((hp >= 0) ? zfA[hp] : 0.f) - ((s0 > 0) ? zfA[s0 - 1] : 0.f);
      int sa = (s0 > 1) ? s0 : 1;
      int sb = (s1 - 1 < 255) ? (s1 - 1) : 255;
      float neg = (sb >= sa) ? (zfA[512 - sa] - zfA[511 - sb]) : 0.f;
      acc += wfA * (pos + neg);
    }
    {
      int s0 = slo(lane, csB), s1 = slo(lane + 1, csB);
      int hp = (s1 < 257 ? s1 : 257) - 1;
      float pos = ((hp >= 0) ? zfB[hp] : 0.f) - ((s0 > 0) ? zfB[s0 - 1] : 0.f);
      int sa = (s0 > 1) ? s0 : 1;
      int sb = (s1 - 1 < 255) ? (s1 - 1) : 255;
      float neg = (sb >= sa) ? (zfB[512 - sa] - zfB[511 - sb]) : 0.f;
      acc += wfB * (pos + neg);
    }
  }
  s_bins[w][lane] = acc;
  __syncthreads();
  if (tid < NB) {
    float s = s_bins[0][tid] + s_bins[1][tid] + s_bins[2][tid] + s_bins[3][tid];
    atomicAdd(&profSum[(size_t)imgG * NB + tid], s);
  }
}

// ---------------------------------------------------------------------------
// Radial bin counts (geometry only).
// ---------------------------------------------------------------------------
__global__ __launch_bounds__(256) void compute_counts(float* __restrict__ cnt)
{
  const int t = threadIdx.x;
  __shared__ float lb[NB];
  if (t < NB) lb[t] = 0.f;
  __syncthreads();
  const int base = blockIdx.x * 2048;
  #pragma unroll
  for (int k = 0; k < 8; ++k) {
    const int idx = base + k * 256 + t;
    const int y  = idx >> 9;
    const int xx = idx & 511;
    const int sy = (y < 256) ? y : y - 512;
    const int sx = (xx < 256) ? xx : xx - 512;
    float r = sqrtf((float)(sy * sy + sx * sx));
    int bb = (int)(r * 0.1953125f);
    if (bb < NB) atomicAdd(&lb[bb], 1.f);
  }
  __syncthreads();
  if (t < NB) atomicAdd(&cnt[t], lb[t]);
}

// ---------------------------------------------------------------------------
// Finalize: profile means -> log_softmax -> KL.
// ---------------------------------------------------------------------------
__global__ __launch_bounds__(256) void finalize_kl(
    const float* __restrict__ profSum, const float* __restrict__ cntg,
    float* __restrict__ out)
{
  const int b = blockIdx.x;
  const int t = threadIdx.x;
  __shared__ float red[256];

  float lxv = -3.0e38f, lrv = -3.0e38f;
  if (t < 150) {
    const int cc  = t / NB;
    const int bin = t - cc * NB;
    const float c = cntg[bin];
    lxv = profSum[(size_t)(b * 3 + cc) * NB + bin] / c;
    lrv = profSum[(size_t)(48 + b * 3 + cc) * NB + bin] / c;
  }
  auto rmax = [&](float v) {
    red[t] = v; __syncthreads();
    for (int s2 = 128; s2 >= 1; s2 >>= 1) {
      if (t < s2) red[t] = fmaxf(red[t], red[t + s2]);
      __syncthreads();
    }
    float rr = red[0]; __syncthreads();
    return rr;
  };
  auto rsum = [&](float v) {
    red[t] = v; __syncthreads();
    for (int s2 = 128; s2 >= 1; s2 >>= 1) {
      if (t < s2) red[t] = red[t] + red[t + s2];
      __syncthreads();
    }
    float rr = red[0]; __syncthreads();
    return rr;
  };
  const float mx  = rmax(lxv);
  const float mr  = rmax(lrv);
  const float sx  = rsum((t < 150) ? expf(lxv - mx) : 0.f);
  const float sr  = rsum((t < 150) ? expf(lrv - mr) : 0.f);
  const float lsx = logf(sx);
  const float lsr = logf(sr);
  float term = 0.f;
  if (t < 150) {
    const float logp = lxv - mx - lsx;
    const float logq = lrv - mr - lsr;
    const float q    = expf(logq);
    term = q * (logq - logp);
  }
  const float div = rsum(term);
  if (t == 0) out[b] = div;
}

// ---------------------------------------------------------------------------
extern "C" void kernel_launch(void* const* d_in, const int* in_sizes, int n_in,
                              void* d_out, int out_size, void* d_ws, size_t ws_size,
                              hipStream_t stream)
{
  const float* x = (const float*)d_in[0];
  const float* r = (const float*)d_in[1];
  float* out     = (float*)d_out;

  // ws layout: [0,19200) profile sums; [19200,19400) counts; then per chunk:
  // interT (bf16x2 spectra, 514KB/img) followed by powerbuf (fp32, 514KB/img).
  float* profSum = (float*)d_ws;
  float* cnt     = (float*)((char*)d_ws + 19200);
  const size_t IM_OFS = 19456;

  const size_t perImgI = (size_t)NCOL * 512 * sizeof(uint32);
  const size_t perImgP = (size_t)NCOL * 512 * sizeof(float);
  const size_t perImg  = perImgI + perImgP;   // ~1.03 MiB
  size_t avail = (ws_size > IM_OFS) ? (ws_size - IM_OFS) : 0;
  int ic = (int)(avail / perImg);
  if (ic > NIMG) ic = NIMG;
  if (ic < 1) ic = 1;

  uint32* interT = (uint32*)((char*)d_ws + IM_OFS);
  float*  pwbuf  = (float*)((char*)d_ws + IM_OFS + (size_t)ic * perImgI);

  hipMemsetAsync(d_ws, 0, IM_OFS, stream);
  hipLaunchKernelGGL(compute_counts, dim3(128), dim3(256), 0, stream, cnt);

  for (int img0 = 0; img0 < NIMG; img0 += ic) {
    const int n = (NIMG - img0 < ic) ? (NIMG - img0) : ic;
    hipLaunchKernelGGL(fft_rows_T, dim3(n * 32), dim3(256), 0, stream,
                       x, r, interT, img0);
    hipLaunchKernelGGL(fft_cols_pow, dim3(n * 33), dim3(256), 0, stream,
                       interT, pwbuf, img0);
    hipLaunchKernelGGL(bin_pow, dim3(n * 33), dim3(256), 0, stream,
                       pwbuf, profSum, img0);
  }
  hipLaunchKernelGGL(finalize_kl, dim3(16), dim3(256), 0, stream,
                     profSum, cnt, out);
}

// Round 14
// 69.432 us; speedup vs baseline: 1.3353x; 1.3353x over previous
//
#include <hip/hip_runtime.h>

// SpectralDivergence: fft2(512x512) power spectrum -> radial profile (50 bins)
// -> per-batch KL divergence between softmaxed profiles of x and reference.
// 96 images (48 x + 48 ref), B=16, C=3, H=W=512. Output: 16 floats.
//
// R14: R12 structure (best: 87.8us; single interT buffer - R13 refuted the
// dirty-line theory but confirmed ANY second big ws buffer poisons rows'
// input re-streaming) + slo() TABLE. cols_bin1 was 54us @ VALUBusy 77%:
// the per-lane slo() (2x sqrt + divergent while-loops, lanes 0..49 all
// different trip counts) is a pure function of (bin, column) -> precomputed
// u16[257][52] table (26KB, one tiny kernel, L2-resident). Also
// launch_bounds(256,8): 17.4KB LDS allows 8 blocks/CU.
// Pre-commit: cols <=44us, total 72-78us, absmax exactly 512.

#define NIMG 96
#define NB 50
#define NCOL 257
#define PHYS(k) ((k) ^ (((k) >> 3) & 7))

typedef unsigned int uint32;
typedef unsigned short ushort16;

__device__ __forceinline__ float2 cadd(float2 a, float2 b){ return make_float2(a.x+b.x, a.y+b.y); }
__device__ __forceinline__ float2 csub(float2 a, float2 b){ return make_float2(a.x-b.x, a.y-b.y); }
__device__ __forceinline__ float2 cmul(float2 a, float2 b){
  return make_float2(fmaf(a.x, b.x, -(a.y*b.y)), fmaf(a.x, b.y, a.y*b.x));
}
__device__ __forceinline__ float2 mul_mi(float2 a){ return make_float2(a.y, -a.x); }  // * -i

// pack complex -> bf16x2 (re high, im low), RNE
__device__ __forceinline__ uint32 bfpack(float re, float im) {
  uint32 ur = __float_as_uint(re); ur += 0x7FFFu + ((ur >> 16) & 1u);
  uint32 ui = __float_as_uint(im); ui += 0x7FFFu + ((ui >> 16) & 1u);
  return (ur & 0xFFFF0000u) | (ui >> 16);
}
__device__ __forceinline__ float2 bfunpack(uint32 u) {
  return make_float2(__uint_as_float(u & 0xFFFF0000u), __uint_as_float(u << 16));
}

// 8 complex values in named registers.
struct C8 { float2 m0, m1, m2, m3, m4, m5, m6, m7; };

// 8-point DFT, natural order (by value).
__device__ __forceinline__ C8 fft8(C8 v) {
  const float C = 0.70710678118654752f;
  float2 t0=cadd(v.m0,v.m4), t1=csub(v.m0,v.m4);
  float2 t2=cadd(v.m2,v.m6), t3m=mul_mi(csub(v.m2,v.m6));
  float2 E0=cadd(t0,t2), E1=cadd(t1,t3m), E2=csub(t0,t2), E3=csub(t1,t3m);
  float2 s0=cadd(v.m1,v.m5), s1=csub(v.m1,v.m5);
  float2 s2=cadd(v.m3,v.m7), s3m=mul_mi(csub(v.m3,v.m7));
  float2 O0=cadd(s0,s2), O1=cadd(s1,s3m), O2=csub(s0,s2), O3=csub(s1,s3m);
  O1 = make_float2(C*(O1.x+O1.y), C*(O1.y-O1.x));      // * W8^1
  O2 = mul_mi(O2);                                      // * W8^2
  O3 = make_float2(C*(O3.y-O3.x), -C*(O3.x+O3.y));      // * W8^3
  C8 r;
  r.m0=cadd(E0,O0); r.m4=csub(E0,O0);
  r.m1=cadd(E1,O1); r.m5=csub(E1,O1);
  r.m2=cadd(E2,O2); r.m6=csub(E2,O2);
  r.m3=cadd(E3,O3); r.m7=csub(E3,O3);
  return r;
}

// twiddle recurrence, dual (shared t chain) and single versions
#define TWAPPLY(XA, XB, W) do { float2 t_ = (W);                        \
  XA.m1=cmul(XA.m1,t_); XB.m1=cmul(XB.m1,t_); t_=cmul(t_,(W));          \
  XA.m2=cmul(XA.m2,t_); XB.m2=cmul(XB.m2,t_); t_=cmul(t_,(W));          \
  XA.m3=cmul(XA.m3,t_); XB.m3=cmul(XB.m3,t_); t_=cmul(t_,(W));          \
  XA.m4=cmul(XA.m4,t_); XB.m4=cmul(XB.m4,t_); t_=cmul(t_,(W));          \
  XA.m5=cmul(XA.m5,t_); XB.m5=cmul(XB.m5,t_); t_=cmul(t_,(W));          \
  XA.m6=cmul(XA.m6,t_); XB.m6=cmul(XB.m6,t_); t_=cmul(t_,(W));          \
  XA.m7=cmul(XA.m7,t_); XB.m7=cmul(XB.m7,t_); } while(0)

#define TWAP1(X, W) do { float2 t_ = (W);                               \
  X.m1=cmul(X.m1,t_); t_=cmul(t_,(W));                                  \
  X.m2=cmul(X.m2,t_); t_=cmul(t_,(W));                                  \
  X.m3=cmul(X.m3,t_); t_=cmul(t_,(W));                                  \
  X.m4=cmul(X.m4,t_); t_=cmul(t_,(W));                                  \
  X.m5=cmul(X.m5,t_); t_=cmul(t_,(W));                                  \
  X.m6=cmul(X.m6,t_); t_=cmul(t_,(W));                                  \
  X.m7=cmul(X.m7,t_); } while(0)

// Dual wave-local 512-pt FFT (two independent FFTs, phase-interleaved).
#define DUAL_FFT512(XA, XB, ZA, ZB, W1, W2, HI, LO) do {                      \
  XA = fft8(XA); XB = fft8(XB);                                               \
  TWAPPLY(XA, XB, W1);                                                        \
  ZA[      8*((HI)^0)+(LO)] = XA.m0;  ZB[      8*((HI)^0)+(LO)] = XB.m0;      \
  ZA[ 64 + 8*((HI)^1)+(LO)] = XA.m1;  ZB[ 64 + 8*((HI)^1)+(LO)] = XB.m1;      \
  ZA[128 + 8*((HI)^2)+(LO)] = XA.m2;  ZB[128 + 8*((HI)^2)+(LO)] = XB.m2;      \
  ZA[192 + 8*((HI)^3)+(LO)] = XA.m3;  ZB[192 + 8*((HI)^3)+(LO)] = XB.m3;      \
  ZA[256 + 8*((HI)^4)+(LO)] = XA.m4;  ZB[256 + 8*((HI)^4)+(LO)] = XB.m4;      \
  ZA[320 + 8*((HI)^5)+(LO)] = XA.m5;  ZB[320 + 8*((HI)^5)+(LO)] = XB.m5;      \
  ZA[384 + 8*((HI)^6)+(LO)] = XA.m6;  ZB[384 + 8*((HI)^6)+(LO)] = XB.m6;      \
  ZA[448 + 8*((HI)^7)+(LO)] = XA.m7;  ZB[448 + 8*((HI)^7)+(LO)] = XB.m7;      \
  __builtin_amdgcn_wave_barrier();                                            \
  XA.m0 = ZA[64*(HI)+8*(0^(HI))+(LO)]; XB.m0 = ZB[64*(HI)+8*(0^(HI))+(LO)];   \
  XA.m1 = ZA[64*(HI)+8*(1^(HI))+(LO)]; XB.m1 = ZB[64*(HI)+8*(1^(HI))+(LO)];   \
  XA.m2 = ZA[64*(HI)+8*(2^(HI))+(LO)]; XB.m2 = ZB[64*(HI)+8*(2^(HI))+(LO)];   \
  XA.m3 = ZA[64*(HI)+8*(3^(HI))+(LO)]; XB.m3 = ZB[64*(HI)+8*(3^(HI))+(LO)];   \
  XA.m4 = ZA[64*(HI)+8*(4^(HI))+(LO)]; XB.m4 = ZB[64*(HI)+8*(4^(HI))+(LO)];   \
  XA.m5 = ZA[64*(HI)+8*(5^(HI))+(LO)]; XB.m5 = ZB[64*(HI)+8*(5^(HI))+(LO)];   \
  XA.m6 = ZA[64*(HI)+8*(6^(HI))+(LO)]; XB.m6 = ZB[64*(HI)+8*(6^(HI))+(LO)];   \
  XA.m7 = ZA[64*(HI)+8*(7^(HI))+(LO)]; XB.m7 = ZB[64*(HI)+8*(7^(HI))+(LO)];   \
  __builtin_amdgcn_wave_barrier();                                            \
  XA = fft8(XA); XB = fft8(XB);                                               \
  TWAPPLY(XA, XB, W2);                                                        \
  ZA[64*(HI)+8*(0^(HI))+((LO)^0)] = XA.m0; ZB[64*(HI)+8*(0^(HI))+((LO)^0)] = XB.m0; \
  ZA[64*(HI)+8*(1^(HI))+((LO)^1)] = XA.m1; ZB[64*(HI)+8*(1^(HI))+((LO)^1)] = XB.m1; \
  ZA[64*(HI)+8*(2^(HI))+((LO)^2)] = XA.m2; ZB[64*(HI)+8*(2^(HI))+((LO)^2)] = XB.m2; \
  ZA[64*(HI)+8*(3^(HI))+((LO)^3)] = XA.m3; ZB[64*(HI)+8*(3^(HI))+((LO)^3)] = XB.m3; \
  ZA[64*(HI)+8*(4^(HI))+((LO)^4)] = XA.m4; ZB[64*(HI)+8*(4^(HI))+((LO)^4)] = XB.m4; \
  ZA[64*(HI)+8*(5^(HI))+((LO)^5)] = XA.m5; ZB[64*(HI)+8*(5^(HI))+((LO)^5)] = XB.m5; \
  ZA[64*(HI)+8*(6^(HI))+((LO)^6)] = XA.m6; ZB[64*(HI)+8*(6^(HI))+((LO)^6)] = XB.m6; \
  ZA[64*(HI)+8*(7^(HI))+((LO)^7)] = XA.m7; ZB[64*(HI)+8*(7^(HI))+((LO)^7)] = XB.m7; \
  __builtin_amdgcn_wave_barrier();                                            \
  XA.m0 = ZA[64*(HI)+8*((LO)^(HI))+(0^(LO))]; XB.m0 = ZB[64*(HI)+8*((LO)^(HI))+(0^(LO))]; \
  XA.m1 = ZA[64*(HI)+8*((LO)^(HI))+(1^(LO))]; XB.m1 = ZB[64*(HI)+8*((LO)^(HI))+(1^(LO))]; \
  XA.m2 = ZA[64*(HI)+8*((LO)^(HI))+(2^(LO))]; XB.m2 = ZB[64*(HI)+8*((LO)^(HI))+(2^(LO))]; \
  XA.m3 = ZA[64*(HI)+8*((LO)^(HI))+(3^(LO))]; XB.m3 = ZB[64*(HI)+8*((LO)^(HI))+(3^(LO))]; \
  XA.m4 = ZA[64*(HI)+8*((LO)^(HI))+(4^(LO))]; XB.m4 = ZB[64*(HI)+8*((LO)^(HI))+(4^(LO))]; \
  XA.m5 = ZA[64*(HI)+8*((LO)^(HI))+(5^(LO))]; XB.m5 = ZB[64*(HI)+8*((LO)^(HI))+(5^(LO))]; \
  XA.m6 = ZA[64*(HI)+8*((LO)^(HI))+(6^(LO))]; XB.m6 = ZB[64*(HI)+8*((LO)^(HI))+(6^(LO))]; \
  XA.m7 = ZA[64*(HI)+8*((LO)^(HI))+(7^(LO))]; XB.m7 = ZB[64*(HI)+8*((LO)^(HI))+(7^(LO))]; \
  __builtin_amdgcn_wave_barrier();                                            \
  XA = fft8(XA); XB = fft8(XB);                                               \
} while(0)

// Single wave-local 512-pt FFT (same exchange layouts, one stream).
#define FFT512_1(X, Z, W1, W2, HI, LO) do {                                   \
  X = fft8(X);                                                                \
  TWAP1(X, W1);                                                               \
  Z[      8*((HI)^0)+(LO)] = X.m0;                                            \
  Z[ 64 + 8*((HI)^1)+(LO)] = X.m1;                                            \
  Z[128 + 8*((HI)^2)+(LO)] = X.m2;                                            \
  Z[192 + 8*((HI)^3)+(LO)] = X.m3;                                            \
  Z[256 + 8*((HI)^4)+(LO)] = X.m4;                                            \
  Z[320 + 8*((HI)^5)+(LO)] = X.m5;                                            \
  Z[384 + 8*((HI)^6)+(LO)] = X.m6;                                            \
  Z[448 + 8*((HI)^7)+(LO)] = X.m7;                                            \
  __builtin_amdgcn_wave_barrier();                                            \
  X.m0 = Z[64*(HI)+8*(0^(HI))+(LO)];                                          \
  X.m1 = Z[64*(HI)+8*(1^(HI))+(LO)];                                          \
  X.m2 = Z[64*(HI)+8*(2^(HI))+(LO)];                                          \
  X.m3 = Z[64*(HI)+8*(3^(HI))+(LO)];                                          \
  X.m4 = Z[64*(HI)+8*(4^(HI))+(LO)];                                          \
  X.m5 = Z[64*(HI)+8*(5^(HI))+(LO)];                                          \
  X.m6 = Z[64*(HI)+8*(6^(HI))+(LO)];                                          \
  X.m7 = Z[64*(HI)+8*(7^(HI))+(LO)];                                          \
  __builtin_amdgcn_wave_barrier();                                            \
  X = fft8(X);                                                                \
  TWAP1(X, W2);                                                               \
  Z[64*(HI)+8*(0^(HI))+((LO)^0)] = X.m0;                                      \
  Z[64*(HI)+8*(1^(HI))+((LO)^1)] = X.m1;                                      \
  Z[64*(HI)+8*(2^(HI))+((LO)^2)] = X.m2;                                      \
  Z[64*(HI)+8*(3^(HI))+((LO)^3)] = X.m3;                                      \
  Z[64*(HI)+8*(4^(HI))+((LO)^4)] = X.m4;                                      \
  Z[64*(HI)+8*(5^(HI))+((LO)^5)] = X.m5;                                      \
  Z[64*(HI)+8*(6^(HI))+((LO)^6)] = X.m6;                                      \
  Z[64*(HI)+8*(7^(HI))+((LO)^7)] = X.m7;                                      \
  __builtin_amdgcn_wave_barrier();                                            \
  X.m0 = Z[64*(HI)+8*((LO)^(HI))+(0^(LO))];                                   \
  X.m1 = Z[64*(HI)+8*((LO)^(HI))+(1^(LO))];                                   \
  X.m2 = Z[64*(HI)+8*((LO)^(HI))+(2^(LO))];                                   \
  X.m3 = Z[64*(HI)+8*((LO)^(HI))+(3^(LO))];                                   \
  X.m4 = Z[64*(HI)+8*((LO)^(HI))+(4^(LO))];                                   \
  X.m5 = Z[64*(HI)+8*((LO)^(HI))+(5^(LO))];                                   \
  X.m6 = Z[64*(HI)+8*((LO)^(HI))+(6^(LO))];                                   \
  X.m7 = Z[64*(HI)+8*((LO)^(HI))+(7^(LO))];                                   \
  __builtin_amdgcn_wave_barrier();                                            \
  X = fft8(X);                                                                \
} while(0)

#define TWIDDLE_W(W1, W2, lane)                                             \
  float2 W1, W2;                                                            \
  {                                                                         \
    float sv, cv;                                                           \
    __sincosf(-6.283185307179586f * (float)(lane) / 512.f, &sv, &cv);       \
    W1 = make_float2(cv, sv);                                               \
    __sincosf(-6.283185307179586f * (float)((lane) & 7) / 64.f, &sv, &cv);  \
    W2 = make_float2(cv, sv);                                               \
  }

// bin of a pixel at |sy|=s in column c
__device__ __forceinline__ int binOf(int s, int cc) {
  return (int)(sqrtf((float)(s * s + cc * cc)) * 0.1953125f);
}
// smallest s in [0,257] with binOf(s,cc) >= b
__device__ __forceinline__ int slo(int b, int cc) {
  if (b <= 0) return 0;
  float t = 26.2144f * (float)(b * b) - (float)(cc * cc);
  int s = (t <= 0.f) ? 0 : (int)ceilf(sqrtf(t));
  if (s > 257) s = 257;
  while (s > 0 && binOf(s - 1, cc) >= b) --s;
  while (s < 257 && binOf(s, cc) < b) ++s;
  return s;
}

// ---------------------------------------------------------------------------
// One-shot: slo table, u16 tab[c*52 + b] for c in [0,257), b in [0,51].
// ---------------------------------------------------------------------------
__global__ __launch_bounds__(256) void build_slo_table(ushort16* __restrict__ tab)
{
  const int idx = blockIdx.x * 256 + threadIdx.x;
  if (idx >= NCOL * 51) return;
  const int c = idx / 51, b = idx - c * 51;
  tab[c * 52 + b] = (ushort16)slo(b, c);
}

// ---------------------------------------------------------------------------
// Row pass (R8 verbatim). interT is written ONLY here.
// ---------------------------------------------------------------------------
__global__ __launch_bounds__(256, 4) void fft_rows_T(
    const float* __restrict__ xin, const float* __restrict__ rin,
    uint32* __restrict__ outT, int img0)
{
  __shared__ float2 s_z[8][512];
  __shared__ uint2  s_stage[64][8];
  const int tid = threadIdx.x, w = tid >> 6, lane = tid & 63;
  const int hi = lane >> 3, lo = lane & 7;
  const int imgL = blockIdx.x >> 5, blkin = blockIdx.x & 31;
  const int img = img0 + imgL;
  const float* base = (img < 48) ? (xin + (size_t)img * 262144)
                                 : (rin + (size_t)(img - 48) * 262144);
  const int rpA = blkin * 8 + w;
  const int rpB = rpA + 4;
  const float* srcA = base + (size_t)rpA * 1024;
  const float* srcB = base + (size_t)rpB * 1024;

  TWIDDLE_W(w1, w2, lane)
  float2* zA = s_z[2*w];
  float2* zB = s_z[2*w + 1];
  uint32* outImg = outT + (size_t)imgL * ((size_t)NCOL * 512);

  C8 xA, xB;
  xA.m0 = make_float2(srcA[      lane], srcA[512 +       lane]);
  xA.m1 = make_float2(srcA[ 64 + lane], srcA[512 +  64 + lane]);
  xA.m2 = make_float2(srcA[128 + lane], srcA[512 + 128 + lane]);
  xA.m3 = make_float2(srcA[192 + lane], srcA[512 + 192 + lane]);
  xA.m4 = make_float2(srcA[256 + lane], srcA[512 + 256 + lane]);
  xA.m5 = make_float2(srcA[320 + lane], srcA[512 + 320 + lane]);
  xA.m6 = make_float2(srcA[384 + lane], srcA[512 + 384 + lane]);
  xA.m7 = make_float2(srcA[448 + lane], srcA[512 + 448 + lane]);
  xB.m0 = make_float2(srcB[      lane], srcB[512 +       lane]);
  xB.m1 = make_float2(srcB[ 64 + lane], srcB[512 +  64 + lane]);
  xB.m2 = make_float2(srcB[128 + lane], srcB[512 + 128 + lane]);
  xB.m3 = make_float2(srcB[192 + lane], srcB[512 + 192 + lane]);
  xB.m4 = make_float2(srcB[256 + lane], srcB[512 + 256 + lane]);
  xB.m5 = make_float2(srcB[320 + lane], srcB[512 + 320 + lane]);
  xB.m6 = make_float2(srcB[384 + lane], srcB[512 + 384 + lane]);
  xB.m7 = make_float2(srcB[448 + lane], srcB[512 + 448 + lane]);

  DUAL_FFT512(xA, xB, zA, zB, w1, w2, hi, lo);

  zA[PHYS(hi + 8*lo +   0)] = xA.m0;  zB[PHYS(hi + 8*lo +   0)] = xB.m0;
  zA[PHYS(hi + 8*lo +  64)] = xA.m1;  zB[PHYS(hi + 8*lo +  64)] = xB.m1;
  zA[PHYS(hi + 8*lo + 128)] = xA.m2;  zB[PHYS(hi + 8*lo + 128)] = xB.m2;
  zA[PHYS(hi + 8*lo + 192)] = xA.m3;  zB[PHYS(hi + 8*lo + 192)] = xB.m3;
  zA[PHYS(hi + 8*lo + 256)] = xA.m4;  zB[PHYS(hi + 8*lo + 256)] = xB.m4;
  zA[PHYS(hi + 8*lo + 320)] = xA.m5;  zB[PHYS(hi + 8*lo + 320)] = xB.m5;
  zA[PHYS(hi + 8*lo + 384)] = xA.m6;  zB[PHYS(hi + 8*lo + 384)] = xB.m6;
  zA[PHYS(hi + 8*lo + 448)] = xA.m7;  zB[PHYS(hi + 8*lo + 448)] = xB.m7;
  __builtin_amdgcn_wave_barrier();

  #pragma unroll
  for (int a = 0; a < 4; ++a) {
    const int k  = 64 * a + lane;
    const int pk = (512 - k) & 511;
    float2 zkA = zA[PHYS(k)], zpA = zA[PHYS(pk)];
    float2 zkB = zB[PHYS(k)], zpB = zB[PHYS(pk)];
    uint32 uA0 = bfpack(0.5f*(zkA.x + zpA.x), 0.5f*(zkA.y - zpA.y));
    uint32 uA1 = bfpack(0.5f*(zkA.y + zpA.y), 0.5f*(zpA.x - zkA.x));
    uint32 uB0 = bfpack(0.5f*(zkB.x + zpB.x), 0.5f*(zkB.y - zpB.y));
    uint32 uB1 = bfpack(0.5f*(zkB.y + zpB.y), 0.5f*(zpB.x - zkB.x));
    s_stage[lane][(w + lane) & 7]     = make_uint2(uA0, uA1);
    s_stage[lane][(w + 4 + lane) & 7] = make_uint2(uB0, uB1);
    __syncthreads();
    const int kk = tid >> 2, jj = (tid & 3) * 2;
    uint2 v0 = s_stage[kk][(jj + kk) & 7];
    uint2 v1 = s_stage[kk][(jj + 1 + kk) & 7];
    *reinterpret_cast<uint4*>(outImg + ((size_t)(64*a + kk) * 512
                                        + 16*blkin + 2*jj)) =
        make_uint4(v0.x, v0.y, v1.x, v1.y);
    __syncthreads();
  }
  if (lane == 0) {
    float2 znA = zA[256], znB = zB[256];
    *reinterpret_cast<uint2*>(outImg + ((size_t)256 * 512 + 2 * rpA)) =
        make_uint2(bfpack(znA.x, 0.f), bfpack(znA.y, 0.f));
    *reinterpret_cast<uint2*>(outImg + ((size_t)256 * 512 + 2 * rpB)) =
        make_uint2(bfpack(znB.x, 0.f), bfpack(znB.y, 0.f));
  }
}

// ---------------------------------------------------------------------------
// Fused col pass, ONE column per wave, slo from table. 17KB LDS,
// launch_bounds(256,8) -> 8 blocks/CU. Block = 4 waves; 65 blocks/image.
// ---------------------------------------------------------------------------
__global__ __launch_bounds__(256, 8) void fft_cols_bin1(
    const uint32* __restrict__ inT, const ushort16* __restrict__ tab,
    float* __restrict__ profSum, int img0)
{
  __shared__ float2 s_z[4][512];    // 16 KB (FFT exchange, then fp32 power)
  __shared__ float s_bins[4][64];   // 1 KB
  const int tid = threadIdx.x, w = tid >> 6, lane = tid & 63;
  const int hi = lane >> 3, lo = lane & 7;
  const int imgL = blockIdx.x / 65, blkin = blockIdx.x - imgL * 65;
  const int imgG = img0 + imgL;
  const int c  = blkin * 4 + w;
  const int cs = (c <= 256) ? c : 256;
  const float wf = (c > 256) ? 0.f : ((c == 0 || c == 256) ? 1.f : 2.f);

  TWIDDLE_W(w1, w2, lane)
  float2* z = s_z[w];
  const uint32* src = inT + ((size_t)(imgL * NCOL + cs)) * 512;
  C8 x;
  x.m0 = bfunpack(src[      lane]);
  x.m1 = bfunpack(src[ 64 + lane]);
  x.m2 = bfunpack(src[128 + lane]);
  x.m3 = bfunpack(src[192 + lane]);
  x.m4 = bfunpack(src[256 + lane]);
  x.m5 = bfunpack(src[320 + lane]);
  x.m6 = bfunpack(src[384 + lane]);
  x.m7 = bfunpack(src[448 + lane]);

  // issue table loads early (L2-hot, independent of FFT)
  int ts0 = 0, ts1 = 0;
  if (lane < NB) {
    ts0 = tab[cs * 52 + lane];
    ts1 = tab[cs * 52 + lane + 1];
  }

  FFT512_1(x, z, w1, w2, hi, lo);

  // power -> LDS in natural k order (reuse z as float[512]; wave-private)
  float* zf = (float*)z;
  const int low6 = hi + 8 * lo;
  zf[low6      ] = x.m0.x*x.m0.x + x.m0.y*x.m0.y;
  zf[low6 +  64] = x.m1.x*x.m1.x + x.m1.y*x.m1.y;
  zf[low6 + 128] = x.m2.x*x.m2.x + x.m2.y*x.m2.y;
  zf[low6 + 192] = x.m3.x*x.m3.x + x.m3.y*x.m3.y;
  zf[low6 + 256] = x.m4.x*x.m4.x + x.m4.y*x.m4.y;
  zf[low6 + 320] = x.m5.x*x.m5.x + x.m5.y*x.m5.y;
  zf[low6 + 384] = x.m6.x*x.m6.x + x.m6.y*x.m6.y;
  zf[low6 + 448] = x.m7.x*x.m7.x + x.m7.y*x.m7.y;
  __builtin_amdgcn_wave_barrier();

  // contiguous 8 per lane (2x b128)
  float4 a0 = *reinterpret_cast<float4*>(&zf[8 * lane]);
  float4 a1 = *reinterpret_cast<float4*>(&zf[8 * lane + 4]);

  // local inclusive prefix over 8
  a0.y += a0.x; a0.z += a0.y; a0.w += a0.z;
  a1.x += a0.w; a1.y += a1.x; a1.z += a1.y; a1.w += a1.z;
  float tot = a1.w;

  // wave inclusive scan of lane totals
  float s = tot;
  #pragma unroll
  for (int d = 1; d < 64; d <<= 1) {
    float t = __shfl_up(s, d);
    if (lane >= d) s += t;
  }
  float off = s - tot;
  a0.x += off; a0.y += off; a0.z += off; a0.w += off;
  a1.x += off; a1.y += off; a1.z += off; a1.w += off;

  *reinterpret_cast<float4*>(&zf[8 * lane])     = a0;
  *reinterpret_cast<float4*>(&zf[8 * lane + 4]) = a1;
  __builtin_amdgcn_wave_barrier();

  // bin extraction: bin b = two prefix differences (boundaries from table)
  float acc = 0.f;
  if (lane < NB) {
    const int s0 = ts0, s1 = ts1;
    int hp = (s1 < 257 ? s1 : 257) - 1;
    float pos = ((hp >= 0) ? zf[hp] : 0.f) - ((s0 > 0) ? zf[s0 - 1] : 0.f);
    int sa = (s0 > 1) ? s0 : 1;
    int sb = (s1 - 1 < 255) ? (s1 - 1) : 255;
    float neg = (sb >= sa) ? (zf[512 - sa] - zf[511 - sb]) : 0.f;
    acc = wf * (pos + neg);
  }
  s_bins[w][lane] = acc;
  __syncthreads();
  if (tid < NB) {
    float ss = s_bins[0][tid] + s_bins[1][tid] + s_bins[2][tid] + s_bins[3][tid];
    atomicAdd(&profSum[(size_t)imgG * NB + tid], ss);
  }
}

// ---------------------------------------------------------------------------
// Radial bin counts (geometry only).
// ---------------------------------------------------------------------------
__global__ __launch_bounds__(256) void compute_counts(float* __restrict__ cnt)
{
  const int t = threadIdx.x;
  __shared__ float lb[NB];
  if (t < NB) lb[t] = 0.f;
  __syncthreads();
  const int base = blockIdx.x * 2048;
  #pragma unroll
  for (int k = 0; k < 8; ++k) {
    const int idx = base + k * 256 + t;
    const int y  = idx >> 9;
    const int xx = idx & 511;
    const int sy = (y < 256) ? y : y - 512;
    const int sx = (xx < 256) ? xx : xx - 512;
    float r = sqrtf((float)(sy * sy + sx * sx));
    int bb = (int)(r * 0.1953125f);
    if (bb < NB) atomicAdd(&lb[bb], 1.f);
  }
  __syncthreads();
  if (t < NB) atomicAdd(&cnt[t], lb[t]);
}

// ---------------------------------------------------------------------------
// Finalize: profile means -> log_softmax -> KL.
// ---------------------------------------------------------------------------
__global__ __launch_bounds__(256) void finalize_kl(
    const float* __restrict__ profSum, const float* __restrict__ cntg,
    float* __restrict__ out)
{
  const int b = blockIdx.x;
  const int t = threadIdx.x;
  __shared__ float red[256];

  float lxv = -3.0e38f, lrv = -3.0e38f;
  if (t < 150) {
    const int cc  = t / NB;
    const int bin = t - cc * NB;
    const float c = cntg[bin];
    lxv = profSum[(size_t)(b * 3 + cc) * NB + bin] / c;
    lrv = profSum[(size_t)(48 + b * 3 + cc) * NB + bin] / c;
  }
  auto rmax = [&](float v) {
    red[t] = v; __syncthreads();
    for (int s2 = 128; s2 >= 1; s2 >>= 1) {
      if (t < s2) red[t] = fmaxf(red[t], red[t + s2]);
      __syncthreads();
    }
    float rr = red[0]; __syncthreads();
    return rr;
  };
  auto rsum = [&](float v) {
    red[t] = v; __syncthreads();
    for (int s2 = 128; s2 >= 1; s2 >>= 1) {
      if (t < s2) red[t] = red[t] + red[t + s2];
      __syncthreads();
    }
    float rr = red[0]; __syncthreads();
    return rr;
  };
  const float mx  = rmax(lxv);
  const float mr  = rmax(lrv);
  const float sx  = rsum((t < 150) ? expf(lxv - mx) : 0.f);
  const float sr  = rsum((t < 150) ? expf(lrv - mr) : 0.f);
  const float lsx = logf(sx);
  const float lsr = logf(sr);
  float term = 0.f;
  if (t < 150) {
    const float logp = lxv - mx - lsx;
    const float logq = lrv - mr - lsr;
    const float q    = expf(logq);
    term = q * (logq - logp);
  }
  const float div = rsum(term);
  if (t == 0) out[b] = div;
}

// ---------------------------------------------------------------------------
extern "C" void kernel_launch(void* const* d_in, const int* in_sizes, int n_in,
                              void* d_out, int out_size, void* d_ws, size_t ws_size,
                              hipStream_t stream)
{
  const float* x = (const float*)d_in[0];
  const float* r = (const float*)d_in[1];
  float* out     = (float*)d_out;

  // ws: [0,19200) profSum; [19200,19400) counts; [19456, 19456+26728) slo
  // table (u16[257][52]); [46592, ...) interT chunks (bf16x2, 514KB/img).
  float* profSum = (float*)d_ws;
  float* cnt     = (float*)((char*)d_ws + 19200);
  ushort16* tab  = (ushort16*)((char*)d_ws + 19456);
  const size_t IM_OFS = 46592;
  uint32* interT = (uint32*)((char*)d_ws + IM_OFS);

  const size_t perImg = (size_t)NCOL * 512 * sizeof(uint32);  // ~514 KiB
  size_t avail = (ws_size > IM_OFS) ? (ws_size - IM_OFS) : 0;
  int ic = (int)(avail / perImg);
  if (ic > NIMG) ic = NIMG;
  if (ic < 1) ic = 1;

  hipMemsetAsync(d_ws, 0, 19456, stream);
  hipLaunchKernelGGL(build_slo_table, dim3(52), dim3(256), 0, stream, tab);
  hipLaunchKernelGGL(compute_counts, dim3(128), dim3(256), 0, stream, cnt);

  for (int img0 = 0; img0 < NIMG; img0 += ic) {
    const int n = (NIMG - img0 < ic) ? (NIMG - img0) : ic;
    hipLaunchKernelGGL(fft_rows_T, dim3(n * 32), dim3(256), 0, stream,
                       x, r, interT, img0);
    hipLaunchKernelGGL(fft_cols_bin1, dim3(n * 65), dim3(256), 0, stream,
                       interT, tab, profSum, img0);
  }
  hipLaunchKernelGGL(finalize_kl, dim3(16), dim3(256), 0, stream,
                     profSum, cnt, out);
}